// Round 14
// baseline (576.557 us; speedup 1.0000x reference)
//
#include <hip/hip_runtime.h>
#include <hip/hip_bf16.h>

#define D 128
#define K1 384
#define H 256
#define O 128
#define BE 64
#define GRIDP 512
#define LDF (K1 + 8)   // fallback path feat leading dim
#define LDHF (H + 8)

typedef __attribute__((ext_vector_type(8))) short bf16x8;
typedef __attribute__((ext_vector_type(4))) float f32x4;

// XOR-swizzle (bits 3-5 of ushort col index; 8-elem groups stay contiguous)
#define SSW(row, col) ((row) * 128 + ((col) ^ (((row) & 7) << 3)))   // staging tiles, col<128
#define HSW(row, col) ((row) * 256 + ((col) ^ (((row) & 7) << 3)))   // h tile, col<256

// lgkm-only barrier: orders LDS, does NOT drain vmcnt (prefetch stays in flight).
#define LGKM_BARRIER()                                                 \
    do {                                                               \
        asm volatile("s_waitcnt lgkmcnt(0)\n\ts_barrier" ::: "memory");\
        __builtin_amdgcn_sched_barrier(0);                             \
    } while (0)

__device__ inline ushort f2b(float f) {
    union { float f; unsigned u; } v; v.f = f;
    unsigned u = v.u;
    unsigned r = (u + 0x7fffu + ((u >> 16) & 1u)) >> 16;   // RNE
    return (ushort)r;
}
__device__ inline ushort4 cvt4(float4 v) {
    ushort4 u; u.x = f2b(v.x); u.y = f2b(v.y); u.z = f2b(v.z); u.w = f2b(v.w); return u;
}
__device__ inline bf16x8 cvt8(f32x4 a, f32x4 b) {
    union { bf16x8 v; ushort u[8]; } w;
    w.u[0] = f2b(a[0]); w.u[1] = f2b(a[1]); w.u[2] = f2b(a[2]); w.u[3] = f2b(a[3]);
    w.u[4] = f2b(b[0]); w.u[5] = f2b(b[1]); w.u[6] = f2b(b[2]); w.u[7] = f2b(b[3]);
    return w.v;
}

// W1t[n][k] = bf16(W1[k][n]) (n<256,k<384) ; W2t[o][k] = bf16(W2[k][o]) (o<128,k<256)
__global__ void prep_weights(const float* __restrict__ W1, const float* __restrict__ W2,
                             ushort* __restrict__ W1t, ushort* __restrict__ W2t) {
    int tid = blockIdx.x * blockDim.x + threadIdx.x;
    if (tid < 256 * 384) {
        int n = tid / 384, k = tid % 384;
        W1t[tid] = f2b(W1[k * 256 + n]);
    } else {
        int t2 = tid - 256 * 384;
        if (t2 < 128 * 256) {
            int o = t2 / 256, k = t2 % 256;
            W2t[t2] = f2b(W2[k * 128 + o]);
        }
    }
}

// Xb[n][d] = bf16(x[n][d]) — 12.8 MB gather table
__global__ __launch_bounds__(256)
void prep_x(const float* __restrict__ x, ushort* __restrict__ Xb, long total8) {
    long t = (long)blockIdx.x * blockDim.x + threadIdx.x;
    if (t < total8) {
        const float* src = x + t * 8;
        float4 v0 = ((const float4*)src)[0], v1 = ((const float4*)src)[1];
        union { bf16x8 v; ushort4 u[2]; } w;
        w.u[0] = cvt4(v0); w.u[1] = cvt4(v1);
        *(bf16x8*)(Xb + t * 8) = w.v;
    }
}

// Persistent pipelined kernel: 512 thr (8 waves), BE=64/tile, weights in registers.
// R14: grid=512 => TWO blocks per CU (launch_bounds(512,4), 128-reg cap — R11's
// exact footprint). While one block sits in barriers/HBM wait, the other drives
// LDS+MFMA: per-CU time drops from LDS+HBM (serial) toward max(LDS, HBM).
__global__ __launch_bounds__(512, 4)
void edge_mlp11(const float* __restrict__ ea, const int* __restrict__ eidx,
                const ushort* __restrict__ Xb,
                const ushort* __restrict__ W1t, const ushort* __restrict__ W2t,
                const float* __restrict__ b1, const float* __restrict__ b2,
                float* __restrict__ out, int E, int ntiles) {
    __shared__ __align__(16) ushort sBuf[24576];   // 48 KB: s0|s1|s2 ; sH aliases s0+s1
    ushort* s0 = sBuf;
    ushort* s1 = sBuf + 8192;
    ushort* s2 = sBuf + 16384;
    ushort* sH = sBuf;

    const int tid = threadIdx.x;
    const int wave = tid >> 6, lane = tid & 63;
    const int row16 = lane & 15, kgrp = lane >> 4;
    const int srow = tid >> 3, oct = tid & 7;     // staging: 8 threads per edge-row

    // ---- persistent per-wave weight fragments (no in-loop global loads) ----
    bf16x8 w1f[12][2];      // phase1: cols [wave*32, +32), fc in {0,1}; ks spans K=384
    #pragma unroll
    for (int ks = 0; ks < 12; ++ks)
        #pragma unroll
        for (int fc = 0; fc < 2; ++fc)
            w1f[ks][fc] = *(const bf16x8*)(W1t + (wave * 32 + fc * 16 + row16) * K1 + ks * 32 + kgrp * 8);
    bf16x8 w2f[8];          // phase2: out cols [wave*16, +16)
    #pragma unroll
    for (int ks = 0; ks < 8; ++ks)
        w2f[ks] = *(const bf16x8*)(W2t + (wave * 16 + row16) * H + ks * 32 + kgrp * 8);
    const float b1v0 = b1[wave * 32 + row16];
    const float b1v1 = b1[wave * 32 + 16 + row16];
    const float b2v  = b2[wave * 16 + row16];

    int t = blockIdx.x;
    if (t >= ntiles) return;

    bf16x8 pxs[2], pxr[2];
    f32x4  pea[4];

    // ---- prologue: stage tile t ----
    {
        long se = (long)t * BE + srow; if (se >= E) se = E - 1;
        int2 ei = *(const int2*)(eidx + 2 * se);
        const ushort* ps = Xb + (long)ei.x * D + oct * 16;
        const ushort* pr = Xb + (long)ei.y * D + oct * 16;
        const float*  pe = ea + se * D + oct * 16;
        #pragma unroll
        for (int j = 0; j < 2; ++j) pxs[j] = *(const bf16x8*)(ps + j * 8);
        #pragma unroll
        for (int j = 0; j < 2; ++j) pxr[j] = *(const bf16x8*)(pr + j * 8);
        #pragma unroll
        for (int j = 0; j < 4; ++j) pea[j] = ((const f32x4*)pe)[j];

        #pragma unroll
        for (int j = 0; j < 2; ++j) *(bf16x8*)(s0 + SSW(srow, oct * 16 + j * 8)) = pxs[j];
        #pragma unroll
        for (int j = 0; j < 2; ++j) *(bf16x8*)(s1 + SSW(srow, oct * 16 + j * 8)) = pxr[j];
        *(bf16x8*)(s2 + SSW(srow, oct * 16 + 0)) = cvt8(pea[0], pea[1]);
        *(bf16x8*)(s2 + SSW(srow, oct * 16 + 8)) = cvt8(pea[2], pea[3]);
    }

    int tn = t + GRIDP;
    int2 ei2;
    {
        int tc = (tn < ntiles) ? tn : (ntiles - 1);
        long se = (long)tc * BE + srow; if (se >= E) se = E - 1;
        ei2 = *(const int2*)(eidx + 2 * se);
    }

    while (true) {
        LGKM_BARRIER();                             // A: staging visible (LDS only)
        const bool hasNext = (tn < ntiles);
        if (hasNext) {
            // issue next tile's loads (stay in flight across phase1+phase2)
            long sen = (long)tn * BE + srow; if (sen >= E) sen = E - 1;
            const ushort* ps = Xb + (long)ei2.x * D + oct * 16;
            const ushort* pr = Xb + (long)ei2.y * D + oct * 16;
            const float*  pe = ea + sen * D + oct * 16;
            #pragma unroll
            for (int j = 0; j < 2; ++j) pxs[j] = *(const bf16x8*)(ps + j * 8);
            #pragma unroll
            for (int j = 0; j < 2; ++j) pxr[j] = *(const bf16x8*)(pr + j * 8);
            #pragma unroll
            for (int j = 0; j < 4; ++j) pea[j] = ((const f32x4*)pe)[j];
            // eidx two tiles ahead
            int tnn = tn + GRIDP;
            int tc = (tnn < ntiles) ? tnn : (ntiles - 1);
            long se2 = (long)tc * BE + srow; if (se2 >= E) se2 = E - 1;
            ei2 = *(const int2*)(eidx + 2 * se2);
        }

        // ---- phase 1: acc = feat(64x384) @ W1 (wave: 64 rows x 32 cols) ----
        f32x4 acc[4][2];
        #pragma unroll
        for (int fr = 0; fr < 4; ++fr) { acc[fr][0] = (f32x4){0,0,0,0}; acc[fr][1] = (f32x4){0,0,0,0}; }

        #pragma unroll
        for (int ks = 0; ks < 12; ++ks) {
            const ushort* sA = (ks < 4) ? s0 : ((ks < 8) ? s1 : s2);
            const int kl = (ks & 3) * 32 + kgrp * 8;
            bf16x8 a[4];
            #pragma unroll
            for (int fr = 0; fr < 4; ++fr)
                a[fr] = *(const bf16x8*)(sA + SSW(fr * 16 + row16, kl));
            #pragma unroll
            for (int fr = 0; fr < 4; ++fr) {
                acc[fr][0] = __builtin_amdgcn_mfma_f32_16x16x32_bf16(a[fr], w1f[ks][0], acc[fr][0], 0, 0, 0);
                acc[fr][1] = __builtin_amdgcn_mfma_f32_16x16x32_bf16(a[fr], w1f[ks][1], acc[fr][1], 0, 0, 0);
            }
        }
        LGKM_BARRIER();                             // B: staging reads done (LDS only)

        // ---- bias + relu -> sH (aliases s0+s1) ----
        #pragma unroll
        for (int fr = 0; fr < 4; ++fr)
            #pragma unroll
            for (int r = 0; r < 4; ++r) {
                int row = fr * 16 + kgrp * 4 + r;
                int swz = (row & 7) << 3;
                sH[row * 256 + ((wave * 32 + row16) ^ swz)]      = f2b(fmaxf(acc[fr][0][r] + b1v0, 0.f));
                sH[row * 256 + ((wave * 32 + 16 + row16) ^ swz)] = f2b(fmaxf(acc[fr][1][r] + b1v1, 0.f));
            }
        LGKM_BARRIER();                             // C: sH visible

        // ---- phase 2: out = h(64x256) @ W2 (wave: 64 rows x 16 cols) + store ----
        f32x4 acc2[4];
        #pragma unroll
        for (int fr = 0; fr < 4; ++fr) acc2[fr] = (f32x4){0,0,0,0};
        #pragma unroll
        for (int ks = 0; ks < 8; ++ks) {
            bf16x8 a[4];
            #pragma unroll
            for (int fr = 0; fr < 4; ++fr)
                a[fr] = *(const bf16x8*)(sH + HSW(fr * 16 + row16, ks * 32 + kgrp * 8));
            #pragma unroll
            for (int fr = 0; fr < 4; ++fr)
                acc2[fr] = __builtin_amdgcn_mfma_f32_16x16x32_bf16(a[fr], w2f[ks], acc2[fr], 0, 0, 0);
        }
        {
            const long e0 = (long)t * BE;
            #pragma unroll
            for (int fr = 0; fr < 4; ++fr)
                #pragma unroll
                for (int r = 0; r < 4; ++r) {
                    long erow = e0 + fr * 16 + kgrp * 4 + r;
                    if (erow < E) out[erow * O + wave * 16 + row16] = acc2[fr][r] + b2v;
                }
        }

        if (!hasNext) break;
        LGKM_BARRIER();                             // D: sH reads done, staging free
        // write next tile's staging; compiler waits counted vmcnt for pxs/pxr/pea
        #pragma unroll
        for (int j = 0; j < 2; ++j) *(bf16x8*)(s0 + SSW(srow, oct * 16 + j * 8)) = pxs[j];
        #pragma unroll
        for (int j = 0; j < 2; ++j) *(bf16x8*)(s1 + SSW(srow, oct * 16 + j * 8)) = pxr[j];
        *(bf16x8*)(s2 + SSW(srow, oct * 16 + 0)) = cvt8(pea[0], pea[1]);
        *(bf16x8*)(s2 + SSW(srow, oct * 16 + 8)) = cvt8(pea[2], pea[3]);

        t = tn; tn += GRIDP;
    }
}

// ---------------- fallback kernel: used only if ws too small ----------------
__global__ __launch_bounds__(256, 2)
void edge_mlp(const float* __restrict__ x, const float* __restrict__ ea,
              const int* __restrict__ eidx,
              const float* __restrict__ b1, const float* __restrict__ b2,
              const ushort* __restrict__ W1t, const ushort* __restrict__ W2t,
              float* __restrict__ out, int E) {
    __shared__ ushort sF[64 * LDF];
    ushort* sH = sF;
    const int tid = threadIdx.x, wave = tid >> 6, lane = tid & 63;
    const int row16 = lane & 15, kgrp = lane >> 4;
    const long e0 = (long)blockIdx.x * 64;
    {
        int i = tid >> 2, p = tid & 3;
        long e = e0 + i; if (e >= E) e = E - 1;
        int s = eidx[2 * e], r = eidx[2 * e + 1];
        const float* src0 = x + (long)s * D + p * 32;
        const float* src1 = x + (long)r * D + p * 32;
        const float* src2 = ea + e * D + p * 32;
        ushort* dst = sF + i * LDF + p * 32;
        #pragma unroll
        for (int j = 0; j < 8; ++j) *(ushort4*)(dst + 0 * D + j * 4) = cvt4(((const float4*)src0)[j]);
        #pragma unroll
        for (int j = 0; j < 8; ++j) *(ushort4*)(dst + 1 * D + j * 4) = cvt4(((const float4*)src1)[j]);
        #pragma unroll
        for (int j = 0; j < 8; ++j) *(ushort4*)(dst + 2 * D + j * 4) = cvt4(((const float4*)src2)[j]);
    }
    __syncthreads();
    f32x4 acc[4][4];
    #pragma unroll
    for (int a = 0; a < 4; ++a)
        #pragma unroll
        for (int b = 0; b < 4; ++b) acc[a][b] = (f32x4){0,0,0,0};
    const int wcol = wave * 64;
    for (int k0 = 0; k0 < K1; k0 += 32) {
        bf16x8 a[4], b[4];
        #pragma unroll
        for (int fr = 0; fr < 4; ++fr)
            a[fr] = *(const bf16x8*)(sF + (fr * 16 + row16) * LDF + k0 + kgrp * 8);
        #pragma unroll
        for (int fc = 0; fc < 4; ++fc)
            b[fc] = *(const bf16x8*)(W1t + (wcol + fc * 16 + row16) * K1 + k0 + kgrp * 8);
        #pragma unroll
        for (int fr = 0; fr < 4; ++fr)
            #pragma unroll
            for (int fc = 0; fc < 4; ++fc)
                acc[fr][fc] = __builtin_amdgcn_mfma_f32_16x16x32_bf16(a[fr], b[fc], acc[fr][fc], 0, 0, 0);
    }
    __syncthreads();
    #pragma unroll
    for (int fc = 0; fc < 4; ++fc) {
        int col = wcol + fc * 16 + row16;
        float bv = b1[col];
        #pragma unroll
        for (int fr = 0; fr < 4; ++fr)
            #pragma unroll
            for (int r = 0; r < 4; ++r) {
                int row = fr * 16 + kgrp * 4 + r;
                sH[row * LDHF + col] = f2b(fmaxf(acc[fr][fc][r] + bv, 0.f));
            }
    }
    __syncthreads();
    f32x4 acc2[4][2];
    #pragma unroll
    for (int a = 0; a < 4; ++a)
        #pragma unroll
        for (int b = 0; b < 2; ++b) acc2[a][b] = (f32x4){0,0,0,0};
    const int wo = wave * 32;
    for (int k0 = 0; k0 < H; k0 += 32) {
        bf16x8 a[4], b[2];
        #pragma unroll
        for (int fr = 0; fr < 4; ++fr)
            a[fr] = *(const bf16x8*)(sH + (fr * 16 + row16) * LDHF + k0 + kgrp * 8);
        #pragma unroll
        for (int fc = 0; fc < 2; ++fc)
            b[fc] = *(const bf16x8*)(W2t + (wo + fc * 16 + row16) * H + k0 + kgrp * 8);
        #pragma unroll
        for (int fr = 0; fr < 4; ++fr)
            #pragma unroll
            for (int fc = 0; fc < 2; ++fc)
                acc2[fr][fc] = __builtin_amdgcn_mfma_f32_16x16x32_bf16(a[fr], b[fc], acc2[fr][fc], 0, 0, 0);
    }
    #pragma unroll
    for (int fc = 0; fc < 2; ++fc) {
        int col = wo + fc * 16 + row16;
        float bv = b2[col];
        #pragma unroll
        for (int fr = 0; fr < 4; ++fr)
            #pragma unroll
            for (int r = 0; r < 4; ++r) {
                long row = e0 + fr * 16 + kgrp * 4 + r;
                if (row < E) out[row * O + col] = acc2[fr][fc][r] + bv;
            }
    }
}

extern "C" void kernel_launch(void* const* d_in, const int* in_sizes, int n_in,
                              void* d_out, int out_size, void* d_ws, size_t ws_size,
                              hipStream_t stream) {
    const float* x  = (const float*)d_in[0];
    const float* ea = (const float*)d_in[1];
    const float* W1 = (const float*)d_in[2];
    const float* b1 = (const float*)d_in[3];
    const float* W2 = (const float*)d_in[4];
    const float* b2 = (const float*)d_in[5];
    const int* eidx = (const int*)d_in[6];
    float* out = (float*)d_out;

    const int E = in_sizes[1] / D;          // 500000
    const int N = in_sizes[0] / D;          // 50000

    ushort* W1t = (ushort*)d_ws;                    // 256*384
    ushort* W2t = W1t + 256 * 384;                  // 128*256
    ushort* Xb  = W2t + 128 * 256;                  // N*128 (12.8 MB)
    size_t need = ((size_t)(256 * 384 + 128 * 256) + (size_t)N * 128) * 2;

    prep_weights<<<512, 256, 0, stream>>>(W1, W2, W1t, W2t);

    if (ws_size >= need) {
        long total8 = (long)N * D / 8;
        int nbx = (int)((total8 + 255) / 256);
        prep_x<<<nbx, 256, 0, stream>>>(x, Xb, total8);
        int ntiles = (E + BE - 1) / BE;
        int grid = (ntiles < GRIDP) ? ntiles : GRIDP;
        edge_mlp11<<<grid, 512, 0, stream>>>(ea, eidx, Xb, W1t, W2t, b1, b2, out, E, ntiles);
    } else {
        int nb = (E + 63) / 64;
        edge_mlp<<<nb, 256, 0, stream>>>(x, ea, eidx, b1, b2, W1t, W2t, out, E);
    }
}

// Round 15
// 249.796 us; speedup vs baseline: 2.3081x; 2.3081x over previous
//
#include <hip/hip_runtime.h>
#include <hip/hip_bf16.h>

#define D 128
#define K1 384
#define H 256
#define O 128
#define BE 64
#define GRIDP 256
#define LDF (K1 + 8)   // fallback path feat leading dim
#define LDHF (H + 8)

typedef __attribute__((ext_vector_type(8))) short bf16x8;
typedef __attribute__((ext_vector_type(4))) float f32x4;

// XOR-swizzle (bits 3-5 of ushort col index; 8-elem groups stay contiguous)
#define SSW(row, col) ((row) * 128 + ((col) ^ (((row) & 7) << 3)))   // staging tiles, col<128
#define HSW(row, col) ((row) * 256 + ((col) ^ (((row) & 7) << 3)))   // h tile, col<256

// lgkm-only barrier: orders LDS, does NOT drain vmcnt (prefetch stays in flight).
#define LGKM_BARRIER()                                                 \
    do {                                                               \
        asm volatile("s_waitcnt lgkmcnt(0)\n\ts_barrier" ::: "memory");\
        __builtin_amdgcn_sched_barrier(0);                             \
    } while (0)

__device__ inline ushort f2b(float f) {
    union { float f; unsigned u; } v; v.f = f;
    unsigned u = v.u;
    unsigned r = (u + 0x7fffu + ((u >> 16) & 1u)) >> 16;   // RNE
    return (ushort)r;
}
__device__ inline ushort4 cvt4(float4 v) {
    ushort4 u; u.x = f2b(v.x); u.y = f2b(v.y); u.z = f2b(v.z); u.w = f2b(v.w); return u;
}
__device__ inline bf16x8 cvt8(f32x4 a, f32x4 b) {
    union { bf16x8 v; ushort u[8]; } w;
    w.u[0] = f2b(a[0]); w.u[1] = f2b(a[1]); w.u[2] = f2b(a[2]); w.u[3] = f2b(a[3]);
    w.u[4] = f2b(b[0]); w.u[5] = f2b(b[1]); w.u[6] = f2b(b[2]); w.u[7] = f2b(b[3]);
    return w.v;
}

// W1t[n][k] = bf16(W1[k][n]) (n<256,k<384) ; W2t[o][k] = bf16(W2[k][o]) (o<128,k<256)
__global__ void prep_weights(const float* __restrict__ W1, const float* __restrict__ W2,
                             ushort* __restrict__ W1t, ushort* __restrict__ W2t) {
    int tid = blockIdx.x * blockDim.x + threadIdx.x;
    if (tid < 256 * 384) {
        int n = tid / 384, k = tid % 384;
        W1t[tid] = f2b(W1[k * 256 + n]);
    } else {
        int t2 = tid - 256 * 384;
        if (t2 < 128 * 256) {
            int o = t2 / 256, k = t2 % 256;
            W2t[t2] = f2b(W2[k * 128 + o]);
        }
    }
}

// Xb[n][d] = bf16(x[n][d]) — 12.8 MB gather table
__global__ __launch_bounds__(256)
void prep_x(const float* __restrict__ x, ushort* __restrict__ Xb, long total8) {
    long t = (long)blockIdx.x * blockDim.x + threadIdx.x;
    if (t < total8) {
        const float* src = x + t * 8;
        float4 v0 = ((const float4*)src)[0], v1 = ((const float4*)src)[1];
        union { bf16x8 v; ushort4 u[2]; } w;
        w.u[0] = cvt4(v0); w.u[1] = cvt4(v1);
        *(bf16x8*)(Xb + t * 8) = w.v;
    }
}

// Persistent pipelined kernel: 512 thr (8 waves), BE=64/tile, weights in registers,
// grid=256 (1 block/CU). R15: double-buffered staging (2x48KB) + dedicated sH (32KB)
// => 2 lgkm-only barriers per tile (was 4). Staging write of t+1 overlaps phase 2.
__global__ __launch_bounds__(512, 2)
void edge_mlp12(const float* __restrict__ ea, const int* __restrict__ eidx,
                const ushort* __restrict__ Xb,
                const ushort* __restrict__ W1t, const ushort* __restrict__ W2t,
                const float* __restrict__ b1, const float* __restrict__ b2,
                float* __restrict__ out, int E, int ntiles) {
    // 128 KB: sA0 (48K) | sA1 (48K) | sH (32K). Each sA = s0|s1|s2 (16K each).
    __shared__ __align__(16) ushort sBuf[65536];
    ushort* sH = sBuf + 49152;

    const int tid = threadIdx.x;
    const int wave = tid >> 6, lane = tid & 63;
    const int row16 = lane & 15, kgrp = lane >> 4;
    const int srow = tid >> 3, oct = tid & 7;     // staging: 8 threads per edge-row

    // ---- persistent per-wave weight fragments (no in-loop global loads) ----
    bf16x8 w1f[12][2];      // phase1: cols [wave*32, +32), fc in {0,1}; ks spans K=384
    #pragma unroll
    for (int ks = 0; ks < 12; ++ks)
        #pragma unroll
        for (int fc = 0; fc < 2; ++fc)
            w1f[ks][fc] = *(const bf16x8*)(W1t + (wave * 32 + fc * 16 + row16) * K1 + ks * 32 + kgrp * 8);
    bf16x8 w2f[8];          // phase2: out cols [wave*16, +16)
    #pragma unroll
    for (int ks = 0; ks < 8; ++ks)
        w2f[ks] = *(const bf16x8*)(W2t + (wave * 16 + row16) * H + ks * 32 + kgrp * 8);
    const float b1v0 = b1[wave * 32 + row16];
    const float b1v1 = b1[wave * 32 + 16 + row16];
    const float b2v  = b2[wave * 16 + row16];

    int t = blockIdx.x;
    if (t >= ntiles) return;

    bf16x8 pxs[2], pxr[2];
    f32x4  pea[4];

    // ---- prologue: stage tile t into sA0 ----
    {
        long se = (long)t * BE + srow; if (se >= E) se = E - 1;
        int2 ei = *(const int2*)(eidx + 2 * se);
        const ushort* ps = Xb + (long)ei.x * D + oct * 16;
        const ushort* pr = Xb + (long)ei.y * D + oct * 16;
        const float*  pe = ea + se * D + oct * 16;
        #pragma unroll
        for (int j = 0; j < 2; ++j) pxs[j] = *(const bf16x8*)(ps + j * 8);
        #pragma unroll
        for (int j = 0; j < 2; ++j) pxr[j] = *(const bf16x8*)(pr + j * 8);
        #pragma unroll
        for (int j = 0; j < 4; ++j) pea[j] = ((const f32x4*)pe)[j];

        #pragma unroll
        for (int j = 0; j < 2; ++j) *(bf16x8*)(sBuf + SSW(srow, oct * 16 + j * 8)) = pxs[j];
        #pragma unroll
        for (int j = 0; j < 2; ++j) *(bf16x8*)(sBuf + 8192 + SSW(srow, oct * 16 + j * 8)) = pxr[j];
        *(bf16x8*)(sBuf + 16384 + SSW(srow, oct * 16 + 0)) = cvt8(pea[0], pea[1]);
        *(bf16x8*)(sBuf + 16384 + SSW(srow, oct * 16 + 8)) = cvt8(pea[2], pea[3]);
    }

    int p = 0;
    int tn = t + GRIDP;
    int2 ei2;
    {
        int tc = (tn < ntiles) ? tn : (ntiles - 1);
        long se = (long)tc * BE + srow; if (se >= E) se = E - 1;
        ei2 = *(const int2*)(eidx + 2 * se);
    }

    while (true) {
        LGKM_BARRIER();                 // TOP: staging(t)->sA[p] visible; sH(t-1) consumed
        const bool hasNext = (tn < ntiles);
        if (hasNext) {
            // issue next tile's loads (in flight across phase1+sH+phase2)
            long sen = (long)tn * BE + srow; if (sen >= E) sen = E - 1;
            const ushort* ps = Xb + (long)ei2.x * D + oct * 16;
            const ushort* pr = Xb + (long)ei2.y * D + oct * 16;
            const float*  pe = ea + sen * D + oct * 16;
            #pragma unroll
            for (int j = 0; j < 2; ++j) pxs[j] = *(const bf16x8*)(ps + j * 8);
            #pragma unroll
            for (int j = 0; j < 2; ++j) pxr[j] = *(const bf16x8*)(pr + j * 8);
            #pragma unroll
            for (int j = 0; j < 4; ++j) pea[j] = ((const f32x4*)pe)[j];
            // eidx two tiles ahead
            int tnn = tn + GRIDP;
            int tc = (tnn < ntiles) ? tnn : (ntiles - 1);
            long se2 = (long)tc * BE + srow; if (se2 >= E) se2 = E - 1;
            ei2 = *(const int2*)(eidx + 2 * se2);
        }

        // ---- phase 1: acc = feat(64x384) @ W1 (wave: 64 rows x 32 cols) ----
        const ushort* sA = sBuf + (p ? 24576 : 0);
        f32x4 acc[4][2];
        #pragma unroll
        for (int fr = 0; fr < 4; ++fr) { acc[fr][0] = (f32x4){0,0,0,0}; acc[fr][1] = (f32x4){0,0,0,0}; }

        #pragma unroll
        for (int ks = 0; ks < 12; ++ks) {
            const ushort* sP = sA + ((ks < 4) ? 0 : ((ks < 8) ? 8192 : 16384));
            const int kl = (ks & 3) * 32 + kgrp * 8;
            bf16x8 a[4];
            #pragma unroll
            for (int fr = 0; fr < 4; ++fr)
                a[fr] = *(const bf16x8*)(sP + SSW(fr * 16 + row16, kl));
            #pragma unroll
            for (int fr = 0; fr < 4; ++fr) {
                acc[fr][0] = __builtin_amdgcn_mfma_f32_16x16x32_bf16(a[fr], w1f[ks][0], acc[fr][0], 0, 0, 0);
                acc[fr][1] = __builtin_amdgcn_mfma_f32_16x16x32_bf16(a[fr], w1f[ks][1], acc[fr][1], 0, 0, 0);
            }
        }

        // ---- bias + relu -> sH (dedicated region; no alias with sA) ----
        #pragma unroll
        for (int fr = 0; fr < 4; ++fr)
            #pragma unroll
            for (int r = 0; r < 4; ++r) {
                int row = fr * 16 + kgrp * 4 + r;
                int swz = (row & 7) << 3;
                sH[row * 256 + ((wave * 32 + row16) ^ swz)]      = f2b(fmaxf(acc[fr][0][r] + b1v0, 0.f));
                sH[row * 256 + ((wave * 32 + 16 + row16) ^ swz)] = f2b(fmaxf(acc[fr][1][r] + b1v1, 0.f));
            }
        LGKM_BARRIER();                 // MID: sH visible; sA[p] reads done

        // ---- phase 2: out = h(64x256) @ W2 (wave: 64 rows x 16 cols) + store ----
        f32x4 acc2[4];
        #pragma unroll
        for (int fr = 0; fr < 4; ++fr) acc2[fr] = (f32x4){0,0,0,0};
        #pragma unroll
        for (int ks = 0; ks < 8; ++ks) {
            bf16x8 a[4];
            #pragma unroll
            for (int fr = 0; fr < 4; ++fr)
                a[fr] = *(const bf16x8*)(sH + HSW(fr * 16 + row16, ks * 32 + kgrp * 8));
            #pragma unroll
            for (int fr = 0; fr < 4; ++fr)
                acc2[fr] = __builtin_amdgcn_mfma_f32_16x16x32_bf16(a[fr], w2f[ks], acc2[fr], 0, 0, 0);
        }
        {
            const long e0 = (long)t * BE;
            #pragma unroll
            for (int fr = 0; fr < 4; ++fr)
                #pragma unroll
                for (int r = 0; r < 4; ++r) {
                    long erow = e0 + fr * 16 + kgrp * 4 + r;
                    if (erow < E) out[erow * O + wave * 16 + row16] = acc2[fr][r] + b2v;
                }
        }

        if (!hasNext) break;
        // ---- staging write t+1 -> sA[p^1] (overlaps phase2/store of other waves;
        //      its readers ran two barriers ago). vmcnt wait here is fully aged. ----
        {
            ushort* sB = sBuf + (p ? 0 : 24576);
            #pragma unroll
            for (int j = 0; j < 2; ++j) *(bf16x8*)(sB + SSW(srow, oct * 16 + j * 8)) = pxs[j];
            #pragma unroll
            for (int j = 0; j < 2; ++j) *(bf16x8*)(sB + 8192 + SSW(srow, oct * 16 + j * 8)) = pxr[j];
            *(bf16x8*)(sB + 16384 + SSW(srow, oct * 16 + 0)) = cvt8(pea[0], pea[1]);
            *(bf16x8*)(sB + 16384 + SSW(srow, oct * 16 + 8)) = cvt8(pea[2], pea[3]);
        }

        p ^= 1; t = tn; tn += GRIDP;
    }
}

// ---------------- fallback kernel: used only if ws too small ----------------
__global__ __launch_bounds__(256, 2)
void edge_mlp(const float* __restrict__ x, const float* __restrict__ ea,
              const int* __restrict__ eidx,
              const float* __restrict__ b1, const float* __restrict__ b2,
              const ushort* __restrict__ W1t, const ushort* __restrict__ W2t,
              float* __restrict__ out, int E) {
    __shared__ ushort sF[64 * LDF];
    ushort* sH = sF;
    const int tid = threadIdx.x, wave = tid >> 6, lane = tid & 63;
    const int row16 = lane & 15, kgrp = lane >> 4;
    const long e0 = (long)blockIdx.x * 64;
    {
        int i = tid >> 2, p = tid & 3;
        long e = e0 + i; if (e >= E) e = E - 1;
        int s = eidx[2 * e], r = eidx[2 * e + 1];
        const float* src0 = x + (long)s * D + p * 32;
        const float* src1 = x + (long)r * D + p * 32;
        const float* src2 = ea + e * D + p * 32;
        ushort* dst = sF + i * LDF + p * 32;
        #pragma unroll
        for (int j = 0; j < 8; ++j) *(ushort4*)(dst + 0 * D + j * 4) = cvt4(((const float4*)src0)[j]);
        #pragma unroll
        for (int j = 0; j < 8; ++j) *(ushort4*)(dst + 1 * D + j * 4) = cvt4(((const float4*)src1)[j]);
        #pragma unroll
        for (int j = 0; j < 8; ++j) *(ushort4*)(dst + 2 * D + j * 4) = cvt4(((const float4*)src2)[j]);
    }
    __syncthreads();
    f32x4 acc[4][4];
    #pragma unroll
    for (int a = 0; a < 4; ++a)
        #pragma unroll
        for (int b = 0; b < 4; ++b) acc[a][b] = (f32x4){0,0,0,0};
    const int wcol = wave * 64;
    for (int k0 = 0; k0 < K1; k0 += 32) {
        bf16x8 a[4], b[4];
        #pragma unroll
        for (int fr = 0; fr < 4; ++fr)
            a[fr] = *(const bf16x8*)(sF + (fr * 16 + row16) * LDF + k0 + kgrp * 8);
        #pragma unroll
        for (int fc = 0; fc < 4; ++fc)
            b[fc] = *(const bf16x8*)(W1t + (wcol + fc * 16 + row16) * K1 + k0 + kgrp * 8);
        #pragma unroll
        for (int fr = 0; fr < 4; ++fr)
            #pragma unroll
            for (int fc = 0; fc < 4; ++fc)
                acc[fr][fc] = __builtin_amdgcn_mfma_f32_16x16x32_bf16(a[fr], b[fc], acc[fr][fc], 0, 0, 0);
    }
    __syncthreads();
    #pragma unroll
    for (int fc = 0; fc < 4; ++fc) {
        int col = wcol + fc * 16 + row16;
        float bv = b1[col];
        #pragma unroll
        for (int fr = 0; fr < 4; ++fr)
            #pragma unroll
            for (int r = 0; r < 4; ++r) {
                int row = fr * 16 + kgrp * 4 + r;
                sH[row * LDHF + col] = f2b(fmaxf(acc[fr][fc][r] + bv, 0.f));
            }
    }
    __syncthreads();
    f32x4 acc2[4][2];
    #pragma unroll
    for (int a = 0; a < 4; ++a)
        #pragma unroll
        for (int b = 0; b < 2; ++b) acc2[a][b] = (f32x4){0,0,0,0};
    const int wo = wave * 32;
    for (int k0 = 0; k0 < H; k0 += 32) {
        bf16x8 a[4], b[2];
        #pragma unroll
        for (int fr = 0; fr < 4; ++fr)
            a[fr] = *(const bf16x8*)(sH + (fr * 16 + row16) * LDHF + k0 + kgrp * 8);
        #pragma unroll
        for (int fc = 0; fc < 2; ++fc)
            b[fc] = *(const bf16x8*)(W2t + (wo + fc * 16 + row16) * H + k0 + kgrp * 8);
        #pragma unroll
        for (int fr = 0; fr < 4; ++fr)
            #pragma unroll
            for (int fc = 0; fc < 2; ++fc)
                acc2[fr][fc] = __builtin_amdgcn_mfma_f32_16x16x32_bf16(a[fr], b[fc], acc2[fr][fc], 0, 0, 0);
    }
    #pragma unroll
    for (int fc = 0; fc < 2; ++fc) {
        int col = wo + fc * 16 + row16;
        float bv = b2[col];
        #pragma unroll
        for (int fr = 0; fr < 4; ++fr)
            #pragma unroll
            for (int r = 0; r < 4; ++r) {
                long row = e0 + fr * 16 + kgrp * 4 + r;
                if (row < E) out[row * O + col] = acc2[fr][fc][r] + bv;
            }
    }
}

extern "C" void kernel_launch(void* const* d_in, const int* in_sizes, int n_in,
                              void* d_out, int out_size, void* d_ws, size_t ws_size,
                              hipStream_t stream) {
    const float* x  = (const float*)d_in[0];
    const float* ea = (const float*)d_in[1];
    const float* W1 = (const float*)d_in[2];
    const float* b1 = (const float*)d_in[3];
    const float* W2 = (const float*)d_in[4];
    const float* b2 = (const float*)d_in[5];
    const int* eidx = (const int*)d_in[6];
    float* out = (float*)d_out;

    const int E = in_sizes[1] / D;          // 500000
    const int N = in_sizes[0] / D;          // 50000

    ushort* W1t = (ushort*)d_ws;                    // 256*384
    ushort* W2t = W1t + 256 * 384;                  // 128*256
    ushort* Xb  = W2t + 128 * 256;                  // N*128 (12.8 MB)
    size_t need = ((size_t)(256 * 384 + 128 * 256) + (size_t)N * 128) * 2;

    prep_weights<<<512, 256, 0, stream>>>(W1, W2, W1t, W2t);

    if (ws_size >= need) {
        long total8 = (long)N * D / 8;
        int nbx = (int)((total8 + 255) / 256);
        prep_x<<<nbx, 256, 0, stream>>>(x, Xb, total8);
        int ntiles = (E + BE - 1) / BE;
        int grid = (ntiles < GRIDP) ? ntiles : GRIDP;
        edge_mlp12<<<grid, 512, 0, stream>>>(ea, eidx, Xb, W1t, W2t, b1, b2, out, E, ntiles);
    } else {
        int nb = (E + 63) / 64;
        edge_mlp<<<nb, 256, 0, stream>>>(x, ea, eidx, b1, b2, W1t, W2t, out, E);
    }
}

// Round 16
// 210.582 us; speedup vs baseline: 2.7379x; 1.1862x over previous
//
#include <hip/hip_runtime.h>
#include <hip/hip_bf16.h>

#define D 128
#define K1 384
#define H 256
#define O 128
#define BE 64
#define GRIDP 256
#define LDF (K1 + 8)   // fallback path feat leading dim
#define LDHF (H + 8)

typedef __attribute__((ext_vector_type(8))) short bf16x8;
typedef __attribute__((ext_vector_type(4))) float f32x4;

// XOR-swizzle (bits 3-5 of ushort col index; aligned 4/8-elem groups stay contiguous)
#define SSW(row, col) ((row) * 128 + ((col) ^ (((row) & 7) << 3)))   // staging tiles, col<128
#define HSW(row, col) ((row) * 256 + ((col) ^ (((row) & 7) << 3)))   // h tile, col<256

// lgkm-only barrier: orders LDS, does NOT drain vmcnt (prefetch stays in flight).
#define LGKM_BARRIER()                                                 \
    do {                                                               \
        asm volatile("s_waitcnt lgkmcnt(0)\n\ts_barrier" ::: "memory");\
        __builtin_amdgcn_sched_barrier(0);                             \
    } while (0)

__device__ inline ushort f2b(float f) {
    union { float f; unsigned u; } v; v.f = f;
    unsigned u = v.u;
    unsigned r = (u + 0x7fffu + ((u >> 16) & 1u)) >> 16;   // RNE
    return (ushort)r;
}
__device__ inline ushort4 cvt4(float4 v) {
    ushort4 u; u.x = f2b(v.x); u.y = f2b(v.y); u.z = f2b(v.z); u.w = f2b(v.w); return u;
}
__device__ inline bf16x8 cvt8(f32x4 a, f32x4 b) {
    union { bf16x8 v; ushort u[8]; } w;
    w.u[0] = f2b(a[0]); w.u[1] = f2b(a[1]); w.u[2] = f2b(a[2]); w.u[3] = f2b(a[3]);
    w.u[4] = f2b(b[0]); w.u[5] = f2b(b[1]); w.u[6] = f2b(b[2]); w.u[7] = f2b(b[3]);
    return w.v;
}

// W1t[n][k] = bf16(W1[k][n]) (n<256,k<384) ; W2t[o][k] = bf16(W2[k][o]) (o<128,k<256)
__global__ void prep_weights(const float* __restrict__ W1, const float* __restrict__ W2,
                             ushort* __restrict__ W1t, ushort* __restrict__ W2t) {
    int tid = blockIdx.x * blockDim.x + threadIdx.x;
    if (tid < 256 * 384) {
        int n = tid / 384, k = tid % 384;
        W1t[tid] = f2b(W1[k * 256 + n]);
    } else {
        int t2 = tid - 256 * 384;
        if (t2 < 128 * 256) {
            int o = t2 / 256, k = t2 % 256;
            W2t[t2] = f2b(W2[k * 128 + o]);
        }
    }
}

// Xb[n][d] = bf16(x[n][d]) — 12.8 MB gather table
__global__ __launch_bounds__(256)
void prep_x(const float* __restrict__ x, ushort* __restrict__ Xb, long total8) {
    long t = (long)blockIdx.x * blockDim.x + threadIdx.x;
    if (t < total8) {
        const float* src = x + t * 8;
        float4 v0 = ((const float4*)src)[0], v1 = ((const float4*)src)[1];
        union { bf16x8 v; ushort4 u[2]; } w;
        w.u[0] = cvt4(v0); w.u[1] = cvt4(v1);
        *(bf16x8*)(Xb + t * 8) = w.v;
    }
}

// Persistent pipelined kernel (R11 structure): 512 thr (8 waves), BE=64/tile,
// weights in registers, grid=256 (1 block/CU), 4 lgkm-only barriers/tile.
// R16: phase-1 MFMA operand SWAP -> D[h-col][edge]; each thread holds 4
// contiguous h-cols per edge => sH write is 8x ushort4 (bank-spread via swizzle)
// instead of 32x u16 at 8-way conflict.
__global__ __launch_bounds__(512, 2)
void edge_mlp13(const float* __restrict__ ea, const int* __restrict__ eidx,
                const ushort* __restrict__ Xb,
                const ushort* __restrict__ W1t, const ushort* __restrict__ W2t,
                const float* __restrict__ b1, const float* __restrict__ b2,
                float* __restrict__ out, int E, int ntiles) {
    __shared__ __align__(16) ushort sBuf[24576];   // 48 KB: s0|s1|s2 ; sH aliases s0+s1
    ushort* s0 = sBuf;
    ushort* s1 = sBuf + 8192;
    ushort* s2 = sBuf + 16384;
    ushort* sH = sBuf;

    const int tid = threadIdx.x;
    const int wave = tid >> 6, lane = tid & 63;
    const int row16 = lane & 15, kgrp = lane >> 4;
    const int srow = tid >> 3, oct = tid & 7;     // staging: 8 threads per edge-row

    // ---- persistent per-wave weight fragments (no in-loop global loads) ----
    bf16x8 w1f[12][2];      // phase1: h-cols [wave*32, +32), fc in {0,1}; ks spans K=384
    #pragma unroll
    for (int ks = 0; ks < 12; ++ks)
        #pragma unroll
        for (int fc = 0; fc < 2; ++fc)
            w1f[ks][fc] = *(const bf16x8*)(W1t + (wave * 32 + fc * 16 + row16) * K1 + ks * 32 + kgrp * 8);
    bf16x8 w2f[8];          // phase2: out cols [wave*16, +16)
    #pragma unroll
    for (int ks = 0; ks < 8; ++ks)
        w2f[ks] = *(const bf16x8*)(W2t + (wave * 16 + row16) * H + ks * 32 + kgrp * 8);
    // swapped-D bias: thread covers h-cols wave*32 + fc*16 + kgrp*4 + (0..3)
    float4 b1q[2];
    #pragma unroll
    for (int fc = 0; fc < 2; ++fc)
        b1q[fc] = *(const float4*)(b1 + wave * 32 + fc * 16 + kgrp * 4);
    const float b2v = b2[wave * 16 + row16];

    int t = blockIdx.x;
    if (t >= ntiles) return;

    bf16x8 pxs[2], pxr[2];
    f32x4  pea[4];

    // ---- prologue: stage tile t ----
    {
        long se = (long)t * BE + srow; if (se >= E) se = E - 1;
        int2 ei = *(const int2*)(eidx + 2 * se);
        const ushort* ps = Xb + (long)ei.x * D + oct * 16;
        const ushort* pr = Xb + (long)ei.y * D + oct * 16;
        const float*  pe = ea + se * D + oct * 16;
        #pragma unroll
        for (int j = 0; j < 2; ++j) pxs[j] = *(const bf16x8*)(ps + j * 8);
        #pragma unroll
        for (int j = 0; j < 2; ++j) pxr[j] = *(const bf16x8*)(pr + j * 8);
        #pragma unroll
        for (int j = 0; j < 4; ++j) pea[j] = ((const f32x4*)pe)[j];

        #pragma unroll
        for (int j = 0; j < 2; ++j) *(bf16x8*)(s0 + SSW(srow, oct * 16 + j * 8)) = pxs[j];
        #pragma unroll
        for (int j = 0; j < 2; ++j) *(bf16x8*)(s1 + SSW(srow, oct * 16 + j * 8)) = pxr[j];
        *(bf16x8*)(s2 + SSW(srow, oct * 16 + 0)) = cvt8(pea[0], pea[1]);
        *(bf16x8*)(s2 + SSW(srow, oct * 16 + 8)) = cvt8(pea[2], pea[3]);
    }

    int tn = t + GRIDP;
    int2 ei2;
    {
        int tc = (tn < ntiles) ? tn : (ntiles - 1);
        long se = (long)tc * BE + srow; if (se >= E) se = E - 1;
        ei2 = *(const int2*)(eidx + 2 * se);
    }

    while (true) {
        LGKM_BARRIER();                             // A: staging visible (LDS only)
        const bool hasNext = (tn < ntiles);
        if (hasNext) {
            // issue next tile's loads (stay in flight across phase1+phase2)
            long sen = (long)tn * BE + srow; if (sen >= E) sen = E - 1;
            const ushort* ps = Xb + (long)ei2.x * D + oct * 16;
            const ushort* pr = Xb + (long)ei2.y * D + oct * 16;
            const float*  pe = ea + sen * D + oct * 16;
            #pragma unroll
            for (int j = 0; j < 2; ++j) pxs[j] = *(const bf16x8*)(ps + j * 8);
            #pragma unroll
            for (int j = 0; j < 2; ++j) pxr[j] = *(const bf16x8*)(pr + j * 8);
            #pragma unroll
            for (int j = 0; j < 4; ++j) pea[j] = ((const f32x4*)pe)[j];
            // eidx two tiles ahead
            int tnn = tn + GRIDP;
            int tc = (tnn < ntiles) ? tnn : (ntiles - 1);
            long se2 = (long)tc * BE + srow; if (se2 >= E) se2 = E - 1;
            ei2 = *(const int2*)(eidx + 2 * se2);
        }

        // ---- phase 1 (SWAPPED): acc[fe][fc] = W1slice x feat^T -> D[h-col][edge] ----
        f32x4 acc[4][2];
        #pragma unroll
        for (int fe = 0; fe < 4; ++fe) { acc[fe][0] = (f32x4){0,0,0,0}; acc[fe][1] = (f32x4){0,0,0,0}; }

        #pragma unroll
        for (int ks = 0; ks < 12; ++ks) {
            const ushort* sA = (ks < 4) ? s0 : ((ks < 8) ? s1 : s2);
            const int kl = (ks & 3) * 32 + kgrp * 8;
            bf16x8 a[4];
            #pragma unroll
            for (int fe = 0; fe < 4; ++fe)
                a[fe] = *(const bf16x8*)(sA + SSW(fe * 16 + row16, kl));
            #pragma unroll
            for (int fe = 0; fe < 4; ++fe) {
                acc[fe][0] = __builtin_amdgcn_mfma_f32_16x16x32_bf16(w1f[ks][0], a[fe], acc[fe][0], 0, 0, 0);
                acc[fe][1] = __builtin_amdgcn_mfma_f32_16x16x32_bf16(w1f[ks][1], a[fe], acc[fe][1], 0, 0, 0);
            }
        }
        LGKM_BARRIER();                             // B: staging reads done (LDS only)

        // ---- bias + relu -> sH: thread writes 4 contiguous h-cols per edge ----
        // edge = fe*16 + row16 ; cols = wave*32 + fc*16 + kgrp*4 + (0..3)
        #pragma unroll
        for (int fe = 0; fe < 4; ++fe) {
            int erow = fe * 16 + row16;
            int base = erow * 256;
            int swz = (erow & 7) << 3;
            #pragma unroll
            for (int fc = 0; fc < 2; ++fc) {
                int colb = wave * 32 + fc * 16 + kgrp * 4;
                ushort4 u;
                u.x = f2b(fmaxf(acc[fe][fc][0] + b1q[fc].x, 0.f));
                u.y = f2b(fmaxf(acc[fe][fc][1] + b1q[fc].y, 0.f));
                u.z = f2b(fmaxf(acc[fe][fc][2] + b1q[fc].z, 0.f));
                u.w = f2b(fmaxf(acc[fe][fc][3] + b1q[fc].w, 0.f));
                *(ushort4*)(sH + base + (colb ^ swz)) = u;
            }
        }
        LGKM_BARRIER();                             // C: sH visible

        // ---- phase 2 (unswapped): out = h(64x256) @ W2 (wave: 64 rows x 16 cols) ----
        f32x4 acc2[4];
        #pragma unroll
        for (int fr = 0; fr < 4; ++fr) acc2[fr] = (f32x4){0,0,0,0};
        #pragma unroll
        for (int ks = 0; ks < 8; ++ks) {
            bf16x8 a[4];
            #pragma unroll
            for (int fr = 0; fr < 4; ++fr)
                a[fr] = *(const bf16x8*)(sH + HSW(fr * 16 + row16, ks * 32 + kgrp * 8));
            #pragma unroll
            for (int fr = 0; fr < 4; ++fr)
                acc2[fr] = __builtin_amdgcn_mfma_f32_16x16x32_bf16(a[fr], w2f[ks], acc2[fr], 0, 0, 0);
        }
        {
            const long e0 = (long)t * BE;
            #pragma unroll
            for (int fr = 0; fr < 4; ++fr)
                #pragma unroll
                for (int r = 0; r < 4; ++r) {
                    long erow = e0 + fr * 16 + kgrp * 4 + r;
                    if (erow < E) out[erow * O + wave * 16 + row16] = acc2[fr][r] + b2v;
                }
        }

        if (!hasNext) break;
        LGKM_BARRIER();                             // D: sH reads done, staging free
        // write next tile's staging; counted vmcnt wait (loads oldest in-order)
        #pragma unroll
        for (int j = 0; j < 2; ++j) *(bf16x8*)(s0 + SSW(srow, oct * 16 + j * 8)) = pxs[j];
        #pragma unroll
        for (int j = 0; j < 2; ++j) *(bf16x8*)(s1 + SSW(srow, oct * 16 + j * 8)) = pxr[j];
        *(bf16x8*)(s2 + SSW(srow, oct * 16 + 0)) = cvt8(pea[0], pea[1]);
        *(bf16x8*)(s2 + SSW(srow, oct * 16 + 8)) = cvt8(pea[2], pea[3]);

        t = tn; tn += GRIDP;
    }
}

// ---------------- fallback kernel: used only if ws too small ----------------
__global__ __launch_bounds__(256, 2)
void edge_mlp(const float* __restrict__ x, const float* __restrict__ ea,
              const int* __restrict__ eidx,
              const float* __restrict__ b1, const float* __restrict__ b2,
              const ushort* __restrict__ W1t, const ushort* __restrict__ W2t,
              float* __restrict__ out, int E) {
    __shared__ ushort sF[64 * LDF];
    ushort* sH = sF;
    const int tid = threadIdx.x, wave = tid >> 6, lane = tid & 63;
    const int row16 = lane & 15, kgrp = lane >> 4;
    const long e0 = (long)blockIdx.x * 64;
    {
        int i = tid >> 2, p = tid & 3;
        long e = e0 + i; if (e >= E) e = E - 1;
        int s = eidx[2 * e], r = eidx[2 * e + 1];
        const float* src0 = x + (long)s * D + p * 32;
        const float* src1 = x + (long)r * D + p * 32;
        const float* src2 = ea + e * D + p * 32;
        ushort* dst = sF + i * LDF + p * 32;
        #pragma unroll
        for (int j = 0; j < 8; ++j) *(ushort4*)(dst + 0 * D + j * 4) = cvt4(((const float4*)src0)[j]);
        #pragma unroll
        for (int j = 0; j < 8; ++j) *(ushort4*)(dst + 1 * D + j * 4) = cvt4(((const float4*)src1)[j]);
        #pragma unroll
        for (int j = 0; j < 8; ++j) *(ushort4*)(dst + 2 * D + j * 4) = cvt4(((const float4*)src2)[j]);
    }
    __syncthreads();
    f32x4 acc[4][4];
    #pragma unroll
    for (int a = 0; a < 4; ++a)
        #pragma unroll
        for (int b = 0; b < 4; ++b) acc[a][b] = (f32x4){0,0,0,0};
    const int wcol = wave * 64;
    for (int k0 = 0; k0 < K1; k0 += 32) {
        bf16x8 a[4], b[4];
        #pragma unroll
        for (int fr = 0; fr < 4; ++fr)
            a[fr] = *(const bf16x8*)(sF + (fr * 16 + row16) * LDF + k0 + kgrp * 8);
        #pragma unroll
        for (int fc = 0; fc < 4; ++fc)
            b[fc] = *(const bf16x8*)(W1t + (wcol + fc * 16 + row16) * K1 + k0 + kgrp * 8);
        #pragma unroll
        for (int fr = 0; fr < 4; ++fr)
            #pragma unroll
            for (int fc = 0; fc < 4; ++fc)
                acc[fr][fc] = __builtin_amdgcn_mfma_f32_16x16x32_bf16(a[fr], b[fc], acc[fr][fc], 0, 0, 0);
    }
    __syncthreads();
    #pragma unroll
    for (int fc = 0; fc < 4; ++fc) {
        int col = wcol + fc * 16 + row16;
        float bv = b1[col];
        #pragma unroll
        for (int fr = 0; fr < 4; ++fr)
            #pragma unroll
            for (int r = 0; r < 4; ++r) {
                int row = fr * 16 + kgrp * 4 + r;
                sH[row * LDHF + col] = f2b(fmaxf(acc[fr][fc][r] + bv, 0.f));
            }
    }
    __syncthreads();
    f32x4 acc2[4][2];
    #pragma unroll
    for (int a = 0; a < 4; ++a)
        #pragma unroll
        for (int b = 0; b < 2; ++b) acc2[a][b] = (f32x4){0,0,0,0};
    const int wo = wave * 32;
    for (int k0 = 0; k0 < H; k0 += 32) {
        bf16x8 a[4], b[2];
        #pragma unroll
        for (int fr = 0; fr < 4; ++fr)
            a[fr] = *(const bf16x8*)(sH + (fr * 16 + row16) * LDHF + k0 + kgrp * 8);
        #pragma unroll
        for (int fc = 0; fc < 2; ++fc)
            b[fc] = *(const bf16x8*)(W2t + (wo + fc * 16 + row16) * H + k0 + kgrp * 8);
        #pragma unroll
        for (int fr = 0; fr < 4; ++fr)
            #pragma unroll
            for (int fc = 0; fc < 2; ++fc)
                acc2[fr][fc] = __builtin_amdgcn_mfma_f32_16x16x32_bf16(a[fr], b[fc], acc2[fr][fc], 0, 0, 0);
    }
    #pragma unroll
    for (int fc = 0; fc < 2; ++fc) {
        int col = wo + fc * 16 + row16;
        float bv = b2[col];
        #pragma unroll
        for (int fr = 0; fr < 4; ++fr)
            #pragma unroll
            for (int r = 0; r < 4; ++r) {
                long row = e0 + fr * 16 + kgrp * 4 + r;
                if (row < E) out[row * O + col] = acc2[fr][fc][r] + bv;
            }
    }
}

extern "C" void kernel_launch(void* const* d_in, const int* in_sizes, int n_in,
                              void* d_out, int out_size, void* d_ws, size_t ws_size,
                              hipStream_t stream) {
    const float* x  = (const float*)d_in[0];
    const float* ea = (const float*)d_in[1];
    const float* W1 = (const float*)d_in[2];
    const float* b1 = (const float*)d_in[3];
    const float* W2 = (const float*)d_in[4];
    const float* b2 = (const float*)d_in[5];
    const int* eidx = (const int*)d_in[6];
    float* out = (float*)d_out;

    const int E = in_sizes[1] / D;          // 500000
    const int N = in_sizes[0] / D;          // 50000

    ushort* W1t = (ushort*)d_ws;                    // 256*384
    ushort* W2t = W1t + 256 * 384;                  // 128*256
    ushort* Xb  = W2t + 128 * 256;                  // N*128 (12.8 MB)
    size_t need = ((size_t)(256 * 384 + 128 * 256) + (size_t)N * 128) * 2;

    prep_weights<<<512, 256, 0, stream>>>(W1, W2, W1t, W2t);

    if (ws_size >= need) {
        long total8 = (long)N * D / 8;
        int nbx = (int)((total8 + 255) / 256);
        prep_x<<<nbx, 256, 0, stream>>>(x, Xb, total8);
        int ntiles = (E + BE - 1) / BE;
        int grid = (ntiles < GRIDP) ? ntiles : GRIDP;
        edge_mlp13<<<grid, 512, 0, stream>>>(ea, eidx, Xb, W1t, W2t, b1, b2, out, E, ntiles);
    } else {
        int nb = (E + 63) / 64;
        edge_mlp<<<nb, 256, 0, stream>>>(x, ea, eidx, b1, b2, W1t, W2t, out, E);
    }
}